// Round 1
// baseline (327.256 us; speedup 1.0000x reference)
//
#include <hip/hip_runtime.h>
#include <stdint.h>

typedef unsigned short u16;
typedef __attribute__((ext_vector_type(8))) short short8;
typedef __attribute__((ext_vector_type(4))) float f32x4;

#define D_DIM 4096
#define M_DIM 4096
#define K_DIM 4096
#define N_DIM 4096

#define BM 128
#define BN 128
#define BK 64

typedef const __attribute__((address_space(1))) void* gas1_t;
typedef __attribute__((address_space(3))) void* las3_t;

__device__ __forceinline__ void g2l16(const void* g, void* l) {
  __builtin_amdgcn_global_load_lds((gas1_t)g, (las3_t)l, 16, 0, 0);
}

// round-to-nearest-even fp32 -> bf16 (finite inputs)
__device__ __forceinline__ u16 f2bf(float f) {
  uint32_t u = __float_as_uint(f);
  uint32_t r = (u + 0x7FFFu + ((u >> 16) & 1u)) >> 16;
  return (u16)r;
}

// ---------------- x: fp32 -> bf16, elementwise ----------------
__global__ void cvt_x(const float* __restrict__ x, u16* __restrict__ xb) {
  int64_t base = ((int64_t)blockIdx.x * blockDim.x + threadIdx.x) * 16;
  float4 f[4];
#pragma unroll
  for (int j = 0; j < 4; ++j) f[j] = *(const float4*)(x + base + j * 4);
  union { u16 u[16]; uint4 q[2]; } o;
#pragma unroll
  for (int j = 0; j < 4; ++j) {
    o.u[4 * j + 0] = f2bf(f[j].x);
    o.u[4 * j + 1] = f2bf(f[j].y);
    o.u[4 * j + 2] = f2bf(f[j].z);
    o.u[4 * j + 3] = f2bf(f[j].w);
  }
  *(uint4*)(xb + base) = o.q[0];
  *(uint4*)(xb + base + 8) = o.q[1];
}

// ---- q_int [K][N] int32 -> Qt [N][K] bf16, zp pre-subtracted ----
__global__ void cvt_q(const int* __restrict__ q, const int* __restrict__ zp,
                      u16* __restrict__ qt) {
  __shared__ u16 L[64][68];  // [k][n], padded stride
  const int n0 = blockIdx.x * 64;
  const int k0 = blockIdx.y * 64;
  const int lc = threadIdx.x & 15;   // col quad index (4 ints)
  const int lr = threadIdx.x >> 4;   // row 0..15

  const int z0 = zp[n0 + lc * 4 + 0];
  const int z1 = zp[n0 + lc * 4 + 1];
  const int z2 = zp[n0 + lc * 4 + 2];
  const int z3 = zp[n0 + lc * 4 + 3];

#pragma unroll
  for (int p = 0; p < 4; ++p) {
    int row = lr + p * 16;
    int4 v = *(const int4*)(q + (int64_t)(k0 + row) * D_DIM + n0 + lc * 4);
    L[row][lc * 4 + 0] = f2bf((float)(v.x - z0));
    L[row][lc * 4 + 1] = f2bf((float)(v.y - z1));
    L[row][lc * 4 + 2] = f2bf((float)(v.z - z2));
    L[row][lc * 4 + 3] = f2bf((float)(v.w - z3));
  }
  __syncthreads();

  const int kq = threadIdx.x & 7;   // 8-wide chunk along k
  const int nn = threadIdx.x >> 3;  // 0..31
#pragma unroll
  for (int p = 0; p < 2; ++p) {
    int n = nn + p * 32;
    union { u16 u[8]; uint4 v; } o;
#pragma unroll
    for (int i = 0; i < 8; ++i) o.u[i] = L[kq * 8 + i][n];
    *(uint4*)(qt + (int64_t)(n0 + n) * K_DIM + k0 + kq * 8) = o.v;
  }
}

// ---------------- GEMM: C[m][n] = (A @ Bt^T)*scale[n] + bias[n] ----------------
// A  : [M][K] bf16 row-major
// Bt : [N][K] bf16 row-major (B transposed)
__global__ __launch_bounds__(256, 3)
void gemm_kernel(const u16* __restrict__ A, const u16* __restrict__ Bt,
                 const float* __restrict__ scale, const float* __restrict__ bias,
                 float* __restrict__ C) {
  __shared__ u16 As[BM * BK];
  __shared__ u16 Bs[BN * BK];

  const int tid = threadIdx.x;
  const int bm0 = blockIdx.y * BM;
  const int bn0 = blockIdx.x * BN;

  const int lane = tid & 63;
  const int w = tid >> 6;
  const int wr = w >> 1, wc = w & 1;

  // staging coords: chunk i covers rows sRow + 32*i, cols sCol..sCol+7
  const int sRow = tid >> 3;
  const int sCol = (tid & 7) * 8;

  const u16* aG = A + (int64_t)(bm0 + sRow) * K_DIM + sCol;
  const u16* bG = Bt + (int64_t)(bn0 + sRow) * K_DIM + sCol;
  u16* aL = &As[tid * 8];
  u16* bL = &Bs[tid * 8];

  f32x4 acc[4][4];
#pragma unroll
  for (int m = 0; m < 4; ++m)
#pragma unroll
    for (int n = 0; n < 4; ++n) acc[m][n] = (f32x4)(0.f);

  const int l15 = lane & 15;
  const int lk = (lane >> 4) * 8;

  for (int kt = 0; kt < K_DIM; kt += BK) {
#pragma unroll
    for (int i = 0; i < 4; ++i)
      g2l16(aG + kt + (int64_t)i * 32 * K_DIM, aL + i * 2048);
#pragma unroll
    for (int i = 0; i < 4; ++i)
      g2l16(bG + kt + (int64_t)i * 32 * K_DIM, bL + i * 2048);
    __syncthreads();

#pragma unroll
    for (int kk = 0; kk < 2; ++kk) {
      short8 af[4], bf[4];
#pragma unroll
      for (int m = 0; m < 4; ++m)
        af[m] = *(const short8*)&As[(wr * 64 + m * 16 + l15) * BK + kk * 32 + lk];
#pragma unroll
      for (int n = 0; n < 4; ++n)
        bf[n] = *(const short8*)&Bs[(wc * 64 + n * 16 + l15) * BK + kk * 32 + lk];
#pragma unroll
      for (int m = 0; m < 4; ++m)
#pragma unroll
        for (int n = 0; n < 4; ++n)
          acc[m][n] = __builtin_amdgcn_mfma_f32_16x16x32_bf16(af[m], bf[n], acc[m][n], 0, 0, 0);
    }
    __syncthreads();
  }

  // epilogue: out = acc*scale[col] + bias[col]
  const int r0 = (lane >> 4) * 4;
#pragma unroll
  for (int n = 0; n < 4; ++n) {
    int col = bn0 + wc * 64 + n * 16 + l15;
    float sc = scale[col];
    float bs = bias[col];
#pragma unroll
    for (int m = 0; m < 4; ++m) {
      int row = bm0 + wr * 64 + m * 16 + r0;
#pragma unroll
      for (int j = 0; j < 4; ++j)
        C[(int64_t)(row + j) * N_DIM + col] = acc[m][n][j] * sc + bs;
    }
  }
}

extern "C" void kernel_launch(void* const* d_in, const int* in_sizes, int n_in,
                              void* d_out, int out_size, void* d_ws, size_t ws_size,
                              hipStream_t stream) {
  const float* x = (const float*)d_in[0];
  const int* q = (const int*)d_in[1];
  const float* scale = (const float*)d_in[2];
  const int* zp = (const int*)d_in[3];
  const float* bias = (const float*)d_in[4];
  float* out = (float*)d_out;

  u16* Xb = (u16*)d_ws;                         // 4096*4096 bf16 = 32 MiB
  u16* Qt = Xb + (size_t)M_DIM * K_DIM;         // 4096*4096 bf16 = 32 MiB

  cvt_x<<<(M_DIM * (int64_t)K_DIM) / (256 * 16), 256, 0, stream>>>(x, Xb);

  dim3 gq(N_DIM / 64, K_DIM / 64);
  cvt_q<<<gq, 256, 0, stream>>>(q, zp, Qt);

  dim3 gg(N_DIM / BN, M_DIM / BM);
  gemm_kernel<<<gg, 256, 0, stream>>>(Xb, Qt, scale, bias, out);
}

// Round 4
// 294.854 us; speedup vs baseline: 1.1099x; 1.1099x over previous
//
#include <hip/hip_runtime.h>
#include <stdint.h>

typedef unsigned short u16;
typedef __attribute__((ext_vector_type(8))) short short8;
typedef __attribute__((ext_vector_type(4))) float f32x4;

#define KD 4096

typedef const __attribute__((address_space(1))) void* gas1_t;
typedef __attribute__((address_space(3))) void* las3_t;

__device__ __forceinline__ void g2l16(const void* g, void* l) {
  __builtin_amdgcn_global_load_lds((gas1_t)g, (las3_t)l, 16, 0, 0);
}

// round-to-nearest-even fp32 -> bf16 (finite inputs)
__device__ __forceinline__ u16 f2bf(float f) {
  uint32_t u = __float_as_uint(f);
  return (u16)((u + 0x7FFFu + ((u >> 16) & 1u)) >> 16);
}

// ---------------- x: fp32 -> bf16, one float4 per thread ----------------
__global__ void cvt_x(const float4* __restrict__ x, uint2* __restrict__ xb) {
  int gid = blockIdx.x * 256 + threadIdx.x;
  float4 f = x[gid];
  union { u16 u[4]; uint2 v; } o;
  o.u[0] = f2bf(f.x); o.u[1] = f2bf(f.y);
  o.u[2] = f2bf(f.z); o.u[3] = f2bf(f.w);
  xb[gid] = o.v;
}

// ---- q_int [K][N] int32 -> Qt [N][K] bf16, zp pre-subtracted ----
__global__ void cvt_q(const int* __restrict__ q, const int* __restrict__ zp,
                      u16* __restrict__ qt) {
  __shared__ u16 Lt[64][66];   // [k][n], +2 pad (b32-write friendly, spread banks)
  const int n0 = blockIdx.x * 64;
  const int k0 = blockIdx.y * 64;
  const int nc = threadIdx.x & 15;   // n quad
  const int kr = threadIdx.x >> 4;   // 0..15

  int z[4];
#pragma unroll
  for (int c = 0; c < 4; ++c) z[c] = zp[n0 + nc * 4 + c];

#pragma unroll
  for (int p = 0; p < 4; ++p) {
    int k = p * 16 + kr;
    int4 v = *(const int4*)(q + (int64_t)(k0 + k) * KD + n0 + nc * 4);
    Lt[k][nc * 4 + 0] = f2bf((float)(v.x - z[0]));
    Lt[k][nc * 4 + 1] = f2bf((float)(v.y - z[1]));
    Lt[k][nc * 4 + 2] = f2bf((float)(v.z - z[2]));
    Lt[k][nc * 4 + 3] = f2bf((float)(v.w - z[3]));
  }
  __syncthreads();

  const int kq = threadIdx.x & 7;
  const int nn = threadIdx.x >> 3;
#pragma unroll
  for (int p = 0; p < 2; ++p) {
    int n = nn + p * 32;
    union { u16 u[8]; uint4 v; } o;
#pragma unroll
    for (int i = 0; i < 8; ++i) o.u[i] = Lt[kq * 8 + i][n];
    *(uint4*)(qt + (int64_t)(n0 + n) * KD + k0 + kq * 8) = o.v;
  }
}

// ---------------- GEMM: 256x256 tile, 8-phase schedule ----------------
// A  : [M][K] bf16 row-major      Bt : [N][K] bf16 row-major
// C[m][n] = (sum_k A[m][k]*Bt[n][k]) * scale[n] + bias[n]
__global__ __launch_bounds__(512, 2)
void gemm8(const u16* __restrict__ A, const u16* __restrict__ Bt,
           const float* __restrict__ scale, const float* __restrict__ bias,
           float* __restrict__ C) {
  __shared__ u16 lds[65536];  // As0 | Bs0 | As1 | Bs1, 32KB each

  const int tid = threadIdx.x;
  // bijective XCD swizzle (256 % 8 == 0)
  const int orig = blockIdx.x;
  const int lid = (orig & 7) * 32 + (orig >> 3);
  const int bm0 = (lid >> 4) * 256;
  const int bn0 = (lid & 15) * 256;

  const int lane = tid & 63;
  const int w = tid >> 6;
  const int wr = w >> 2;       // 0..1
  const int wc = w & 3;        // 0..3
  const int l15 = lane & 15;
  const int q4 = lane >> 4;    // 0..3 (k quad)
  const int l7 = l15 & 7;      // read-side swizzle key

  // staging slice: row_local = tid>>3, swizzled source chunk
  const int rl = tid >> 3;
  const int csw = (tid & 7) ^ (rl & 7);
  const u16* gA = A + (int64_t)(bm0 + rl) * KD + csw * 8;
  const u16* gB = Bt + (int64_t)(bn0 + rl) * KD + csw * 8;

#define STA(b, qq, kt) g2l16(gA + (int64_t)(qq) * 64 * KD + (kt), &lds[(b) * 32768 + (qq) * 4096 + tid * 8])
#define STB(b, qq, kt) g2l16(gB + (int64_t)(qq) * 64 * KD + (kt), &lds[16384 + (b) * 32768 + (qq) * 4096 + tid * 8])

#define RD_A(mh)                                                              \
  do {                                                                        \
    _Pragma("unroll") for (int m = 0; m < 4; ++m) {                           \
      const int row = wr * 128 + (mh) * 64 + m * 16 + l15;                    \
      _Pragma("unroll") for (int kk = 0; kk < 2; ++kk)                        \
        ar[m][kk] = *(const short8*)&Ab[row * 64 + (((kk * 4 + q4) ^ l7) * 8)]; \
    }                                                                         \
  } while (0)

#define RD_B(nn0)                                                             \
  do {                                                                        \
    _Pragma("unroll") for (int n = 0; n < 2; ++n) {                           \
      const int col = wc * 64 + ((nn0) + n) * 16 + l15;                       \
      _Pragma("unroll") for (int kk = 0; kk < 2; ++kk)                        \
        br[(nn0) + n][kk] = *(const short8*)&Bb[col * 64 + (((kk * 4 + q4) ^ l7) * 8)]; \
    }                                                                         \
  } while (0)

#define MFMA_Q(mb, nn0)                                                       \
  do {                                                                        \
    __builtin_amdgcn_s_setprio(1);                                            \
    _Pragma("unroll") for (int m = 0; m < 4; ++m)                             \
      _Pragma("unroll") for (int n = 0; n < 2; ++n)                           \
        _Pragma("unroll") for (int kk = 0; kk < 2; ++kk)                      \
          acc[(mb) + m][(nn0) + n] = __builtin_amdgcn_mfma_f32_16x16x32_bf16( \
              ar[m][kk], br[(nn0) + n][kk], acc[(mb) + m][(nn0) + n], 0, 0, 0); \
    __builtin_amdgcn_s_setprio(0);                                            \
  } while (0)

#define LGKM0 asm volatile("s_waitcnt lgkmcnt(0)" ::: "memory")
#define BAR __builtin_amdgcn_s_barrier()

  f32x4 acc[8][4];
#pragma unroll
  for (int m = 0; m < 8; ++m)
#pragma unroll
    for (int n = 0; n < 4; ++n) acc[m][n] = (f32x4)(0.f);

  short8 ar[4][2], br[4][2];

  // ---- prologue: stage tile 0 into buf 0; leave Aq1,Aq3 in flight ----
  STB(0, 0, 0); STB(0, 1, 0); STB(0, 2, 0); STB(0, 3, 0);
  STA(0, 0, 0); STA(0, 2, 0); STA(0, 1, 0); STA(0, 3, 0);
  asm volatile("s_waitcnt vmcnt(2)" ::: "memory");
  BAR;

  int cur = 0;
  for (int t = 0; t < 63; ++t) {
    const int ktn = (t + 1) * 64;
    const u16* __restrict__ Ab = &lds[cur * 32768];
    const u16* __restrict__ Bb = &lds[16384 + cur * 32768];
    const int nb = cur ^ 1;

    // ---- phase 0: mh0 x nh0 ----
    RD_A(0);
    RD_B(0);
    STB(nb, 0, ktn); STB(nb, 1, ktn);
    BAR; LGKM0;
    MFMA_Q(0, 0);
    BAR;

    // ---- phase 1: mh0 x nh1 ----
    RD_B(2);
    STB(nb, 2, ktn); STB(nb, 3, ktn);
    asm volatile("s_waitcnt vmcnt(4)" ::: "memory");  // tile t Aq1,Aq3 landed
    BAR; LGKM0;
    MFMA_Q(0, 2);
    BAR;

    // ---- phase 2: mh1 x nh0 ----
    RD_A(1);
    STA(nb, 0, ktn); STA(nb, 2, ktn);
    BAR; LGKM0;
    MFMA_Q(4, 0);
    BAR;

    // ---- phase 3: mh1 x nh1 ----
    STA(nb, 1, ktn); STA(nb, 3, ktn);
    asm volatile("s_waitcnt vmcnt(2)" ::: "memory");  // t+1: B*,Aq0,Aq2 landed
    BAR; LGKM0;
    MFMA_Q(4, 2);
    BAR;

    cur ^= 1;
  }

  // ---- last tile (t = 63): no staging, drain ----
  {
    const u16* __restrict__ Ab = &lds[cur * 32768];
    const u16* __restrict__ Bb = &lds[16384 + cur * 32768];
    RD_A(0);
    RD_B(0);
    BAR; LGKM0;
    MFMA_Q(0, 0);
    BAR;

    RD_B(2);
    asm volatile("s_waitcnt vmcnt(0)" ::: "memory");  // Aq1,Aq3 of tile 63
    BAR; LGKM0;
    MFMA_Q(0, 2);
    BAR;

    RD_A(1);
    BAR; LGKM0;
    MFMA_Q(4, 0);
    BAR;

    MFMA_Q(4, 2);
  }

  // ---- epilogue: out = acc*scale[col] + bias[col] ----
  const int r4 = q4 * 4;
#pragma unroll
  for (int n = 0; n < 4; ++n) {
    const int col = bn0 + wc * 64 + n * 16 + l15;
    const float sc = scale[col];
    const float bs = bias[col];
#pragma unroll
    for (int mi = 0; mi < 8; ++mi) {
      const int row = bm0 + wr * 128 + mi * 16 + r4;
#pragma unroll
      for (int j = 0; j < 4; ++j)
        C[(int64_t)(row + j) * KD + col] = acc[mi][n][j] * sc + bs;
    }
  }
}

extern "C" void kernel_launch(void* const* d_in, const int* in_sizes, int n_in,
                              void* d_out, int out_size, void* d_ws, size_t ws_size,
                              hipStream_t stream) {
  const float* x = (const float*)d_in[0];
  const int* q = (const int*)d_in[1];
  const float* scale = (const float*)d_in[2];
  const int* zp = (const int*)d_in[3];
  const float* bias = (const float*)d_in[4];
  float* out = (float*)d_out;

  u16* Xb = (u16*)d_ws;                    // 32 MiB
  u16* Qt = Xb + (size_t)4096 * 4096;      // 32 MiB

  cvt_x<<<16384, 256, 0, stream>>>((const float4*)x, (uint2*)Xb);

  dim3 gq(4096 / 64, 4096 / 64);
  cvt_q<<<gq, 256, 0, stream>>>(q, zp, Qt);

  gemm8<<<256, 512, 0, stream>>>(Xb, Qt, scale, bias, out);
}

// Round 6
// 288.004 us; speedup vs baseline: 1.1363x; 1.0238x over previous
//
#include <hip/hip_runtime.h>
#include <stdint.h>

typedef unsigned short u16;
typedef __attribute__((ext_vector_type(8))) short short8;
typedef __attribute__((ext_vector_type(4))) float f32x4;

#define KD 4096

typedef const __attribute__((address_space(1))) void* gas1_t;
typedef __attribute__((address_space(3))) void* las3_t;

__device__ __forceinline__ void g2l16(const void* g, void* l) {
  __builtin_amdgcn_global_load_lds((gas1_t)g, (las3_t)l, 16, 0, 0);
}

// round-to-nearest-even fp32 -> bf16 (finite inputs)
__device__ __forceinline__ u16 f2bf(float f) {
  uint32_t u = __float_as_uint(f);
  return (u16)((u + 0x7FFFu + ((u >> 16) & 1u)) >> 16);
}

// ---- fused conversion:
//   blocks [0, 4096):     q_int [K][N] int32 -> Qt [N][K] bf16 (zp pre-subtracted)
//   blocks [4096, 20480): x fp32 -> bf16 elementwise
__global__ __launch_bounds__(256)
void cvt_fused(const float4* __restrict__ x, const int* __restrict__ q,
               const int* __restrict__ zp, uint2* __restrict__ xb,
               u16* __restrict__ qt) {
  const int b = blockIdx.x;
  if (b >= 4096) {
    // ---- x conversion ----
    int gid = (b - 4096) * 256 + threadIdx.x;
    float4 f = x[gid];
    union { u16 u[4]; uint2 v; } o;
    o.u[0] = f2bf(f.x); o.u[1] = f2bf(f.y);
    o.u[2] = f2bf(f.z); o.u[3] = f2bf(f.w);
    xb[gid] = o.v;
    return;
  }
  // ---- q transpose+convert: 64(k) x 64(n) tile ----
  // Pack k-pairs into u32 so the LDS transpose runs at 4B granularity.
  // Row stride 68 u32 = 272 B = 16B-aligned so the uint4 LDS writes are legal.
  __shared__ uint32_t P[32][68];  // [k_pair][n]
  const int n0 = (b & 63) * 64;
  const int k0 = (b >> 6) * 64;
  const int nc = threadIdx.x & 15;   // 4-column group
  const int kr = threadIdx.x >> 4;   // 0..15

  int z[4];
#pragma unroll
  for (int j = 0; j < 4; ++j) z[j] = zp[n0 + nc * 4 + j];

#pragma unroll
  for (int s = 0; s < 2; ++s) {
    const int kp = kr + s * 16;           // pair index 0..31
    const int64_t rb = (int64_t)(k0 + kp * 2) * KD + n0 + nc * 4;
    int4 r0 = *(const int4*)(q + rb);
    int4 r1 = *(const int4*)(q + rb + KD);
    uint4 w;
    w.x = (uint32_t)f2bf((float)(r0.x - z[0])) | ((uint32_t)f2bf((float)(r1.x - z[0])) << 16);
    w.y = (uint32_t)f2bf((float)(r0.y - z[1])) | ((uint32_t)f2bf((float)(r1.y - z[1])) << 16);
    w.z = (uint32_t)f2bf((float)(r0.z - z[2])) | ((uint32_t)f2bf((float)(r1.z - z[2])) << 16);
    w.w = (uint32_t)f2bf((float)(r0.w - z[3])) | ((uint32_t)f2bf((float)(r1.w - z[3])) << 16);
    *(uint4*)&P[kp][nc * 4] = w;
  }
  __syncthreads();

  const int kq = threadIdx.x & 7;    // 8-u16 chunk along k
  const int nn = threadIdx.x >> 3;   // 0..31
#pragma unroll
  for (int p = 0; p < 2; ++p) {
    const int n = nn + p * 32;
    uint4 v;
    v.x = P[kq * 4 + 0][n];
    v.y = P[kq * 4 + 1][n];
    v.z = P[kq * 4 + 2][n];
    v.w = P[kq * 4 + 3][n];
    *(uint4*)(qt + (int64_t)(n0 + n) * KD + k0 + kq * 8) = v;
  }
}

// ---------------- GEMM: 256x256 tile, 2-barrier/tile pipeline ----------------
// A  : [M][K] bf16 row-major      Bt : [N][K] bf16 row-major
// C[m][n] = (sum_k A[m][k]*Bt[n][k]) * scale[n] + bias[n]
//
// Sync skeleton per K-tile (the round-5 race fix):
//   BAR1                      -- all waves done READING buf nb (tile t-1)
//   STAGE(nb, t+1) x8         -- issue; 16 outstanding
//   s_waitcnt vmcnt(8)        -- MY tile-t loads landed (oldest 8, in-order)
//   BAR2                      -- EVERYONE's tile-t loads landed (publication)
//   compute on cur, barrier-free
__global__ __launch_bounds__(512, 2)
void gemm8(const u16* __restrict__ A, const u16* __restrict__ Bt,
           const float* __restrict__ scale, const float* __restrict__ bias,
           float* __restrict__ C) {
  __shared__ u16 lds[65536];  // As0 | Bs0 | As1 | Bs1, 32KB each

  const int tid = threadIdx.x;
  // bijective XCD swizzle (256 % 8 == 0)
  const int orig = blockIdx.x;
  const int lid = (orig & 7) * 32 + (orig >> 3);
  const int bm0 = (lid >> 4) * 256;
  const int bn0 = (lid & 15) * 256;

  const int lane = tid & 63;
  const int w = tid >> 6;
  const int wr = w >> 2;       // 0..1
  const int wc = w & 3;        // 0..3
  const int l15 = lane & 15;
  const int q4 = lane >> 4;    // 0..3 (k quad)
  const int l7 = l15 & 7;      // read-side swizzle key

  // staging slice: row_local = tid>>3, swizzled source chunk
  const int rl = tid >> 3;
  const int csw = (tid & 7) ^ (rl & 7);
  const u16* gA = A + (int64_t)(bm0 + rl) * KD + csw * 8;
  const u16* gB = Bt + (int64_t)(bn0 + rl) * KD + csw * 8;

#define STA(b_, qq, kt) g2l16(gA + (int64_t)(qq) * 64 * KD + (kt), &lds[(b_) * 32768 + (qq) * 4096 + tid * 8])
#define STB(b_, qq, kt) g2l16(gB + (int64_t)(qq) * 64 * KD + (kt), &lds[16384 + (b_) * 32768 + (qq) * 4096 + tid * 8])

#define RD_A(mh)                                                              \
  do {                                                                        \
    _Pragma("unroll") for (int m = 0; m < 4; ++m) {                           \
      const int row = wr * 128 + (mh) * 64 + m * 16 + l15;                    \
      _Pragma("unroll") for (int kk = 0; kk < 2; ++kk)                        \
        ar[m][kk] = *(const short8*)&Ab[row * 64 + (((kk * 4 + q4) ^ l7) * 8)]; \
    }                                                                         \
  } while (0)

#define RD_B(nn0)                                                             \
  do {                                                                        \
    _Pragma("unroll") for (int n = 0; n < 2; ++n) {                           \
      const int col = wc * 64 + ((nn0) + n) * 16 + l15;                       \
      _Pragma("unroll") for (int kk = 0; kk < 2; ++kk)                        \
        br[(nn0) + n][kk] = *(const short8*)&Bb[col * 64 + (((kk * 4 + q4) ^ l7) * 8)]; \
    }                                                                         \
  } while (0)

#define MFMA_Q(mb, nn0)                                                       \
  do {                                                                        \
    __builtin_amdgcn_s_setprio(1);                                            \
    _Pragma("unroll") for (int m = 0; m < 4; ++m)                             \
      _Pragma("unroll") for (int n = 0; n < 2; ++n)                           \
        _Pragma("unroll") for (int kk = 0; kk < 2; ++kk)                      \
          acc[(mb) + m][(nn0) + n] = __builtin_amdgcn_mfma_f32_16x16x32_bf16( \
              ar[m][kk], br[(nn0) + n][kk], acc[(mb) + m][(nn0) + n], 0, 0, 0); \
    __builtin_amdgcn_s_setprio(0);                                            \
  } while (0)

#define BAR __builtin_amdgcn_s_barrier()
#define SCHED0 __builtin_amdgcn_sched_barrier(0)
#define CFENCE asm volatile("" ::: "memory")
#define VMC8 asm volatile("s_waitcnt vmcnt(8)" ::: "memory")
#define VMC0 asm volatile("s_waitcnt vmcnt(0)" ::: "memory")

  f32x4 acc[8][4];
#pragma unroll
  for (int m = 0; m < 8; ++m)
#pragma unroll
    for (int n = 0; n < 4; ++n) acc[m][n] = (f32x4)(0.f);

  short8 ar[4][2], br[4][2];

  // ---- prologue: issue tile-0 stages into buf 0 ----
  STB(0, 0, 0); STB(0, 1, 0); STB(0, 2, 0); STB(0, 3, 0);
  STA(0, 0, 0); STA(0, 1, 0); STA(0, 2, 0); STA(0, 3, 0);

  int cur = 0;
  for (int t = 0; t < 63; ++t) {
    const int ktn = (t + 1) * 64;
    const u16* __restrict__ Ab = &lds[cur * 32768];
    const u16* __restrict__ Bb = &lds[16384 + cur * 32768];
    const int nb = cur ^ 1;

    SCHED0; CFENCE;
    BAR;  // BAR1: all waves done reading nb (their reads were consumed by
          // lgkm-gated MFMAs that precede this point in program order)
    STB(nb, 0, ktn); STB(nb, 1, ktn); STB(nb, 2, ktn); STB(nb, 3, ktn);
    STA(nb, 0, ktn); STA(nb, 1, ktn); STA(nb, 2, ktn); STA(nb, 3, ktn);
    VMC8;  // my tile-t loads (oldest 8) landed; tile t+1's stay in flight
    BAR;   // BAR2: publication -- everyone's tile-t loads landed
    SCHED0; CFENCE;

    // barrier-free tile body: compiler pipelines ds_read<->MFMA with
    // counted lgkmcnt; waves on a SIMD slip to overlap LDS with MFMA.
    RD_A(0);
    RD_B(0);
    RD_B(2);
    MFMA_Q(0, 0);
    MFMA_Q(0, 2);
    RD_A(1);           // reuses ar[] (A0 dead after Q(0,2))
    MFMA_Q(4, 0);
    MFMA_Q(4, 2);

    cur ^= 1;
  }

  // ---- last tile (t = 63): no staging, drain ----
  {
    const u16* __restrict__ Ab = &lds[cur * 32768];
    const u16* __restrict__ Bb = &lds[16384 + cur * 32768];
    SCHED0; CFENCE;
    BAR;
    VMC0;  // tile-63 loads (mine) landed
    BAR;   // publication
    SCHED0; CFENCE;
    RD_A(0);
    RD_B(0);
    RD_B(2);
    MFMA_Q(0, 0);
    MFMA_Q(0, 2);
    RD_A(1);
    MFMA_Q(4, 0);
    MFMA_Q(4, 2);
  }

  // ---- epilogue: out = acc*scale[col] + bias[col] ----
  const int r4 = q4 * 4;
#pragma unroll
  for (int n = 0; n < 4; ++n) {
    const int col = bn0 + wc * 64 + n * 16 + l15;
    const float sc = scale[col];
    const float bs = bias[col];
#pragma unroll
    for (int mi = 0; mi < 8; ++mi) {
      const int row = bm0 + wr * 128 + mi * 16 + r4;
#pragma unroll
      for (int j = 0; j < 4; ++j)
        C[(int64_t)(row + j) * KD + col] = acc[mi][n][j] * sc + bs;
    }
  }
}

extern "C" void kernel_launch(void* const* d_in, const int* in_sizes, int n_in,
                              void* d_out, int out_size, void* d_ws, size_t ws_size,
                              hipStream_t stream) {
  const float* x = (const float*)d_in[0];
  const int* q = (const int*)d_in[1];
  const float* scale = (const float*)d_in[2];
  const int* zp = (const int*)d_in[3];
  const float* bias = (const float*)d_in[4];
  float* out = (float*)d_out;

  u16* Xb = (u16*)d_ws;                    // 32 MiB
  u16* Qt = Xb + (size_t)4096 * 4096;      // 32 MiB

  // blocks [0,4096): q transpose+convert; [4096,20480): x convert
  cvt_fused<<<20480, 256, 0, stream>>>((const float4*)x, q, zp,
                                       (uint2*)Xb, Qt);

  gemm8<<<256, 512, 0, stream>>>(Xb, Qt, scale, bias, out);
}

// Round 7
// 279.225 us; speedup vs baseline: 1.1720x; 1.0314x over previous
//
#include <hip/hip_runtime.h>
#include <stdint.h>

typedef unsigned short u16;
typedef __attribute__((ext_vector_type(8))) short short8;
typedef __attribute__((ext_vector_type(4))) float f32x4;

#define KD 4096

typedef const __attribute__((address_space(1))) void* gas1_t;
typedef __attribute__((address_space(3))) void* las3_t;

__device__ __forceinline__ void g2l16(const void* g, void* l) {
  __builtin_amdgcn_global_load_lds((gas1_t)g, (las3_t)l, 16, 0, 0);
}

// round-to-nearest-even fp32 -> bf16 (finite inputs)
__device__ __forceinline__ u16 f2bf(float f) {
  uint32_t u = __float_as_uint(f);
  return (u16)((u + 0x7FFFu + ((u >> 16) & 1u)) >> 16);
}

// ---- fused conversion (UNCHANGED from round 6 -- control variable):
//   blocks [0, 4096):     q_int [K][N] int32 -> Qt [N][K] bf16 (zp pre-subtracted)
//   blocks [4096, 20480): x fp32 -> bf16 elementwise
__global__ __launch_bounds__(256)
void cvt_fused(const float4* __restrict__ x, const int* __restrict__ q,
               const int* __restrict__ zp, uint2* __restrict__ xb,
               u16* __restrict__ qt) {
  const int b = blockIdx.x;
  if (b >= 4096) {
    int gid = (b - 4096) * 256 + threadIdx.x;
    float4 f = x[gid];
    union { u16 u[4]; uint2 v; } o;
    o.u[0] = f2bf(f.x); o.u[1] = f2bf(f.y);
    o.u[2] = f2bf(f.z); o.u[3] = f2bf(f.w);
    xb[gid] = o.v;
    return;
  }
  __shared__ uint32_t P[32][68];  // [k_pair][n], stride 272B (16B-aligned)
  const int n0 = (b & 63) * 64;
  const int k0 = (b >> 6) * 64;
  const int nc = threadIdx.x & 15;
  const int kr = threadIdx.x >> 4;

  int z[4];
#pragma unroll
  for (int j = 0; j < 4; ++j) z[j] = zp[n0 + nc * 4 + j];

#pragma unroll
  for (int s = 0; s < 2; ++s) {
    const int kp = kr + s * 16;
    const int64_t rb = (int64_t)(k0 + kp * 2) * KD + n0 + nc * 4;
    int4 r0 = *(const int4*)(q + rb);
    int4 r1 = *(const int4*)(q + rb + KD);
    uint4 w;
    w.x = (uint32_t)f2bf((float)(r0.x - z[0])) | ((uint32_t)f2bf((float)(r1.x - z[0])) << 16);
    w.y = (uint32_t)f2bf((float)(r0.y - z[1])) | ((uint32_t)f2bf((float)(r1.y - z[1])) << 16);
    w.z = (uint32_t)f2bf((float)(r0.z - z[2])) | ((uint32_t)f2bf((float)(r1.z - z[2])) << 16);
    w.w = (uint32_t)f2bf((float)(r0.w - z[3])) | ((uint32_t)f2bf((float)(r1.w - z[3])) << 16);
    *(uint4*)&P[kp][nc * 4] = w;
  }
  __syncthreads();

  const int kq = threadIdx.x & 7;
  const int nn = threadIdx.x >> 3;
#pragma unroll
  for (int p = 0; p < 2; ++p) {
    const int n = nn + p * 32;
    uint4 v;
    v.x = P[kq * 4 + 0][n];
    v.y = P[kq * 4 + 1][n];
    v.z = P[kq * 4 + 2][n];
    v.w = P[kq * 4 + 3][n];
    *(uint4*)(qt + (int64_t)(n0 + n) * KD + k0 + kq * 8) = v;
  }
}

// ---------------- GEMM: 256x256 tile, 8-phase, rebalanced waits ----------------
// A  : [M][K] bf16 row-major      Bt : [N][K] bf16 row-major
// C[m][n] = (sum_k A[m][k]*Bt[n][k]) * scale[n] + bias[n]
//
// Per K-tile (4 phases), staging tile t+1 in consumption order:
//   ph0: RD A0-half + B-lo | stage B0,B1,A0 | lgkm(8) | BAR lgkm0 MFMA(0,0) BAR
//   ph1: RD B-hi           | stage B2,B3,A2 | vmcnt(6): t's A1,A3 landed | BAR lgkm0 MFMA(0,2) BAR
//   ph2: RD A1-half        | stage A1,A3   |                              BAR lgkm0 MFMA(4,0) BAR
//   ph3:                   |               | vmcnt(2): t+1's first-6 landed | BAR lgkm0 MFMA(4,2) BAR
// Publication: each vmcnt precedes a barrier all waves cross before the
// dependent ds_reads (race-fix invariant from round 5).
__global__ __launch_bounds__(512, 2)
void gemm8(const u16* __restrict__ A, const u16* __restrict__ Bt,
           const float* __restrict__ scale, const float* __restrict__ bias,
           float* __restrict__ C) {
  __shared__ u16 lds[65536];  // buf0: A@0 B@16384 | buf1: A@32768 B@49152

  const int tid = threadIdx.x;
  const int orig = blockIdx.x;
  const int lid = (orig & 7) * 32 + (orig >> 3);   // bijective XCD swizzle
  const int bm0 = (lid >> 4) * 256;
  const int bn0 = (lid & 15) * 256;

  const int lane = tid & 63;
  const int w = tid >> 6;
  const int wr = w >> 2;       // 0..1
  const int wc = w & 3;        // 0..3
  const int l15 = lane & 15;
  const int q4 = lane >> 4;    // 0..3
  const int l7 = l15 & 7;      // read-side swizzle key

  const int rl = tid >> 3;
  const int csw = (tid & 7) ^ (rl & 7);            // write-side swizzle (inverse)
  const u16* gA = A + (int64_t)(bm0 + rl) * KD + csw * 8;
  const u16* gB = Bt + (int64_t)(bn0 + rl) * KD + csw * 8;

#define STA(OFF, qq, kt) g2l16(gA + (int64_t)(qq) * 64 * KD + (kt), &lds[(OFF) + (qq) * 4096 + tid * 8])
#define STB(OFF, qq, kt) g2l16(gB + (int64_t)(qq) * 64 * KD + (kt), &lds[(OFF) + (qq) * 4096 + tid * 8])

#define RD_A(AOFF, mh)                                                        \
  do {                                                                        \
    _Pragma("unroll") for (int m = 0; m < 4; ++m) {                           \
      const int row = wr * 128 + (mh) * 64 + m * 16 + l15;                    \
      _Pragma("unroll") for (int kk = 0; kk < 2; ++kk)                        \
        ar[m][kk] = *(const short8*)&lds[(AOFF) + row * 64 + (((kk * 4 + q4) ^ l7) * 8)]; \
    }                                                                         \
  } while (0)

#define RD_B(BOFF, nn0)                                                       \
  do {                                                                        \
    _Pragma("unroll") for (int n = 0; n < 2; ++n) {                           \
      const int col = wc * 64 + ((nn0) + n) * 16 + l15;                       \
      _Pragma("unroll") for (int kk = 0; kk < 2; ++kk)                        \
        br[(nn0) + n][kk] = *(const short8*)&lds[(BOFF) + col * 64 + (((kk * 4 + q4) ^ l7) * 8)]; \
    }                                                                         \
  } while (0)

#define MFMA_Q(mb, nn0)                                                       \
  do {                                                                        \
    __builtin_amdgcn_s_setprio(1);                                            \
    _Pragma("unroll") for (int m = 0; m < 4; ++m)                             \
      _Pragma("unroll") for (int n = 0; n < 2; ++n)                           \
        _Pragma("unroll") for (int kk = 0; kk < 2; ++kk)                      \
          acc[(mb) + m][(nn0) + n] = __builtin_amdgcn_mfma_f32_16x16x32_bf16( \
              ar[m][kk], br[(nn0) + n][kk], acc[(mb) + m][(nn0) + n], 0, 0, 0); \
    __builtin_amdgcn_s_setprio(0);                                            \
  } while (0)

#define BAR __builtin_amdgcn_s_barrier()
#define SCHED0 __builtin_amdgcn_sched_barrier(0)
#define LGKM0 do { asm volatile("s_waitcnt lgkmcnt(0)" ::: "memory"); SCHED0; } while (0)
#define LGKM8 asm volatile("s_waitcnt lgkmcnt(8)" ::: "memory")
#define VMC6 asm volatile("s_waitcnt vmcnt(6)" ::: "memory")
#define VMC2 asm volatile("s_waitcnt vmcnt(2)" ::: "memory")
#define VMC0 asm volatile("s_waitcnt vmcnt(0)" ::: "memory")
#define WNONE

// One K-tile: read from (AOFF,BOFF); if STG, stage tile t+1 into (SAOFF,SBOFF)
// at k-offset KTN. W1/W2 are the ph1/ph3 vmcnt statements.
#define K_TILE(AOFF, BOFF, SAOFF, SBOFF, KTN, STG, W1, W2)                    \
  do {                                                                        \
    /* ph0 */                                                                 \
    RD_A(AOFF, 0);                                                            \
    RD_B(BOFF, 0);                                                            \
    if (STG) { STB(SBOFF, 0, KTN); STB(SBOFF, 1, KTN); STA(SAOFF, 0, KTN); }  \
    LGKM8;                                                                    \
    BAR; LGKM0;                                                               \
    MFMA_Q(0, 0);                                                             \
    BAR;                                                                      \
    /* ph1 */                                                                 \
    RD_B(BOFF, 2);                                                            \
    if (STG) { STB(SBOFF, 2, KTN); STB(SBOFF, 3, KTN); STA(SAOFF, 2, KTN); }  \
    W1;                                                                       \
    BAR; LGKM0;                                                               \
    MFMA_Q(0, 2);                                                             \
    BAR;                                                                      \
    /* ph2 */                                                                 \
    RD_A(AOFF, 1);                                                            \
    if (STG) { STA(SAOFF, 1, KTN); STA(SAOFF, 3, KTN); }                      \
    BAR; LGKM0;                                                               \
    MFMA_Q(4, 0);                                                             \
    BAR;                                                                      \
    /* ph3 */                                                                 \
    W2;                                                                       \
    BAR; LGKM0;                                                               \
    MFMA_Q(4, 2);                                                             \
    BAR;                                                                      \
  } while (0)

  f32x4 acc[8][4];
#pragma unroll
  for (int m = 0; m < 8; ++m)
#pragma unroll
    for (int n = 0; n < 4; ++n) acc[m][n] = (f32x4)(0.f);

  short8 ar[4][2], br[4][2];

  // ---- prologue: stage tile 0 into buf 0, consumption order; leave A1,A3 in flight
  STB(16384, 0, 0); STB(16384, 1, 0); STA(0, 0, 0);
  STB(16384, 2, 0); STB(16384, 3, 0); STA(0, 2, 0);
  STA(0, 1, 0); STA(0, 3, 0);
  VMC2;   // first-6 (B0..3, A0, A2) landed
  BAR;    // publication

  for (int i = 0; i < 31; ++i) {
    const int kt1 = (2 * i + 1) * 64;
    const int kt2 = (2 * i + 2) * 64;
    K_TILE(0, 16384, 32768, 49152, kt1, 1, VMC6, VMC2);   // tile 2i   (buf0 -> stage buf1)
    K_TILE(32768, 49152, 0, 16384, kt2, 1, VMC6, VMC2);   // tile 2i+1 (buf1 -> stage buf0)
  }
  // tile 62 (buf0), stage tile 63 -> buf1
  K_TILE(0, 16384, 32768, 49152, 63 * 64, 1, VMC6, VMC2);
  // tile 63 (buf1), no staging; ph1 waits its A1,A3 (only 2 outstanding)
  K_TILE(32768, 49152, 0, 16384, 0, 0, VMC0, WNONE);

  // ---- epilogue: out = acc*scale[col] + bias[col] ----
  const int r4 = q4 * 4;
#pragma unroll
  for (int n = 0; n < 4; ++n) {
    const int col = bn0 + wc * 64 + n * 16 + l15;
    const float sc = scale[col];
    const float bs = bias[col];
#pragma unroll
    for (int mi = 0; mi < 8; ++mi) {
      const int row = bm0 + wr * 128 + mi * 16 + r4;
#pragma unroll
      for (int j = 0; j < 4; ++j)
        C[(int64_t)(row + j) * KD + col] = acc[mi][n][j] * sc + bs;
    }
  }
}

extern "C" void kernel_launch(void* const* d_in, const int* in_sizes, int n_in,
                              void* d_out, int out_size, void* d_ws, size_t ws_size,
                              hipStream_t stream) {
  const float* x = (const float*)d_in[0];
  const int* q = (const int*)d_in[1];
  const float* scale = (const float*)d_in[2];
  const int* zp = (const int*)d_in[3];
  const float* bias = (const float*)d_in[4];
  float* out = (float*)d_out;

  u16* Xb = (u16*)d_ws;                    // 32 MiB
  u16* Qt = Xb + (size_t)4096 * 4096;      // 32 MiB

  cvt_fused<<<20480, 256, 0, stream>>>((const float4*)x, q, zp,
                                       (uint2*)Xb, Qt);

  gemm8<<<256, 512, 0, stream>>>(Xb, Qt, scale, bias, out);
}

// Round 9
// 275.993 us; speedup vs baseline: 1.1857x; 1.0117x over previous
//
#include <hip/hip_runtime.h>
#include <stdint.h>

typedef unsigned short u16;
typedef __attribute__((ext_vector_type(8))) short short8;
typedef __attribute__((ext_vector_type(4))) float f32x4;

#define KD 4096

typedef const __attribute__((address_space(1))) void* gas1_t;
typedef __attribute__((address_space(3))) void* las3_t;

__device__ __forceinline__ void g2l16(const void* g, void* l) {
  __builtin_amdgcn_global_load_lds((gas1_t)g, (las3_t)l, 16, 0, 0);
}

// round-to-nearest-even fp32 -> bf16 (finite inputs)
__device__ __forceinline__ u16 f2bf(float f) {
  uint32_t u = __float_as_uint(f);
  return (u16)((u + 0x7FFFu + ((u >> 16) & 1u)) >> 16);
}

// ---- fused conversion (UNCHANGED -- control variable):
//   blocks [0, 4096):     q_int [K][N] int32 -> Qt [N][K] bf16 (zp pre-subtracted)
//   blocks [4096, 20480): x fp32 -> bf16 elementwise
__global__ __launch_bounds__(256)
void cvt_fused(const float4* __restrict__ x, const int* __restrict__ q,
               const int* __restrict__ zp, uint2* __restrict__ xb,
               u16* __restrict__ qt) {
  const int b = blockIdx.x;
  if (b >= 4096) {
    int gid = (b - 4096) * 256 + threadIdx.x;
    float4 f = x[gid];
    union { u16 u[4]; uint2 v; } o;
    o.u[0] = f2bf(f.x); o.u[1] = f2bf(f.y);
    o.u[2] = f2bf(f.z); o.u[3] = f2bf(f.w);
    xb[gid] = o.v;
    return;
  }
  __shared__ uint32_t P[32][68];  // [k_pair][n], stride 272B (16B-aligned)
  const int n0 = (b & 63) * 64;
  const int k0 = (b >> 6) * 64;
  const int nc = threadIdx.x & 15;
  const int kr = threadIdx.x >> 4;

  int z[4];
#pragma unroll
  for (int j = 0; j < 4; ++j) z[j] = zp[n0 + nc * 4 + j];

#pragma unroll
  for (int s = 0; s < 2; ++s) {
    const int kp = kr + s * 16;
    const int64_t rb = (int64_t)(k0 + kp * 2) * KD + n0 + nc * 4;
    int4 r0 = *(const int4*)(q + rb);
    int4 r1 = *(const int4*)(q + rb + KD);
    uint4 w;
    w.x = (uint32_t)f2bf((float)(r0.x - z[0])) | ((uint32_t)f2bf((float)(r1.x - z[0])) << 16);
    w.y = (uint32_t)f2bf((float)(r0.y - z[1])) | ((uint32_t)f2bf((float)(r1.y - z[1])) << 16);
    w.z = (uint32_t)f2bf((float)(r0.z - z[2])) | ((uint32_t)f2bf((float)(r1.z - z[2])) << 16);
    w.w = (uint32_t)f2bf((float)(r0.w - z[3])) | ((uint32_t)f2bf((float)(r1.w - z[3])) << 16);
    *(uint4*)&P[kp][nc * 4] = w;
  }
  __syncthreads();

  const int kq = threadIdx.x & 7;
  const int nn = threadIdx.x >> 3;
#pragma unroll
  for (int p = 0; p < 2; ++p) {
    const int n = nn + p * 32;
    uint4 v;
    v.x = P[kq * 4 + 0][n];
    v.y = P[kq * 4 + 1][n];
    v.z = P[kq * 4 + 2][n];
    v.w = P[kq * 4 + 3][n];
    *(uint4*)(qt + (int64_t)(n0 + n) * KD + k0 + kq * 8) = v;
  }
}

// ---------------- GEMM: 256x256 tile, 8-phase, 4-phase wait margins ----------------
// A  : [M][K] bf16 row-major      Bt : [N][K] bf16 row-major
// C[m][n] = (sum_k A[m][k]*Bt[n][k]) * scale[n] + bias[n]
//
// B staged in column-parity units (32-col blocks of Bt-rows):
//   ev0={0-31,64-95} ev1={128-159,192-223} od0={32-63,96-127} od1={160-191,224-255}
// Per K-tile, staging tile t+1:
//   ph0: RD A-half0 + B-even | stage Bev0,Bev1,A0,A2 | vmcnt(6): prev Bod landed
//   ph1: RD B-odd            | stage Bod0,Bod1       | vmcnt(6): prev A1,A3 landed
//   ph2: RD A-half1          | stage A1,A3           |
//   ph3:                     |                        | vmcnt(4): t+1 ev-four landed
// Every load has a 4-phase (~1000cy) margin; >=4 loads always in flight.
// Each vmcnt precedes a barrier all waves cross before the dependent ds_reads.
__global__ __launch_bounds__(512, 2)
void gemm8(const u16* __restrict__ A, const u16* __restrict__ Bt,
           const float* __restrict__ scale, const float* __restrict__ bias,
           float* __restrict__ C) {
  __shared__ u16 lds[65536];  // buf0: A@0 B@16384 | buf1: A@32768 B@49152

  const int tid = threadIdx.x;
  const int orig = blockIdx.x;
  const int lid = (orig & 7) * 32 + (orig >> 3);   // bijective XCD swizzle
  const int bm0 = (lid >> 4) * 256;
  const int bn0 = (lid & 15) * 256;

  const int lane = tid & 63;
  const int w = tid >> 6;
  const int wr = w >> 2;       // 0..1
  const int wc = w & 3;        // 0..3
  const int l15 = lane & 15;
  const int q4 = lane >> 4;    // 0..3
  const int l7 = l15 & 7;      // read-side swizzle key

  const int rl = tid >> 3;                         // staging row-in-unit 0..63
  const int csw = (tid & 7) ^ (rl & 7);            // write-side swizzle (inverse)
  const u16* gA = A + (int64_t)(bm0 + rl) * KD + csw * 8;
  const int rr = (rl & 31) + ((rl >> 5) << 6);     // 0..31, 64..95
  const u16* gBe = Bt + (int64_t)(bn0 + rr) * KD + csw * 8;
  const u16* gBo = gBe + (int64_t)32 * KD;

  const int bq = (wc & 1) * 32 + l15;              // B row-in-unit base
  const int bub = wc >> 1;                         // B unit base

#define STA(OFF, qq, kt) g2l16(gA + (int64_t)(qq) * 64 * KD + (kt), &lds[(OFF) + (qq) * 4096 + tid * 8])
#define STBE(OFF, uu, kt) g2l16(gBe + (int64_t)(uu) * 128 * KD + (kt), &lds[(OFF) + (uu) * 4096 + tid * 8])
#define STBO(OFF, uu, kt) g2l16(gBo + (int64_t)(uu) * 128 * KD + (kt), &lds[(OFF) + (2 + (uu)) * 4096 + tid * 8])

#define RD_A(AOFF, mh)                                                        \
  do {                                                                        \
    _Pragma("unroll") for (int m = 0; m < 4; ++m) {                           \
      const int row = wr * 128 + (mh) * 64 + m * 16 + l15;                    \
      _Pragma("unroll") for (int kk = 0; kk < 2; ++kk)                        \
        ar[m][kk] = *(const short8*)&lds[(AOFF) + row * 64 + (((kk * 4 + q4) ^ l7) * 8)]; \
    }                                                                         \
  } while (0)

// unit = nn0 + (wc>>1), row-in-unit = (wc&1)*32 + n*16 + l15 (key l7 unchanged)
#define RD_B(BOFF, nn0)                                                       \
  do {                                                                        \
    _Pragma("unroll") for (int n = 0; n < 2; ++n) {                           \
      const int ro = ((nn0) + bub) * 4096 + (bq + n * 16) * 64;               \
      _Pragma("unroll") for (int kk = 0; kk < 2; ++kk)                        \
        br[(nn0) + n][kk] = *(const short8*)&lds[(BOFF) + ro + (((kk * 4 + q4) ^ l7) * 8)]; \
    }                                                                         \
  } while (0)

#define MFMA_Q(mb, nn0)                                                       \
  do {                                                                        \
    __builtin_amdgcn_s_setprio(1);                                            \
    _Pragma("unroll") for (int m = 0; m < 4; ++m)                             \
      _Pragma("unroll") for (int n = 0; n < 2; ++n)                           \
        _Pragma("unroll") for (int kk = 0; kk < 2; ++kk)                      \
          acc[(mb) + m][(nn0) + n] = __builtin_amdgcn_mfma_f32_16x16x32_bf16( \
              ar[m][kk], br[(nn0) + n][kk], acc[(mb) + m][(nn0) + n], 0, 0, 0); \
    __builtin_amdgcn_s_setprio(0);                                            \
  } while (0)

#define BAR __builtin_amdgcn_s_barrier()
#define SCHED0 __builtin_amdgcn_sched_barrier(0)
#define LGKM0 do { asm volatile("s_waitcnt lgkmcnt(0)" ::: "memory"); SCHED0; } while (0)
#define LGKM8 asm volatile("s_waitcnt lgkmcnt(8)" ::: "memory")
#define VMC6 asm volatile("s_waitcnt vmcnt(6)" ::: "memory")
#define VMC4 asm volatile("s_waitcnt vmcnt(4)" ::: "memory")
#define VMC2 asm volatile("s_waitcnt vmcnt(2)" ::: "memory")
#define VMC0 asm volatile("s_waitcnt vmcnt(0)" ::: "memory")
#define WNONE

// One K-tile; waits W0 (ph0), W1 (ph1), W2 (ph3) per the margin audit above.
#define K_TILE(AOFF, BOFF, SAOFF, SBOFF, KTN, STG, W0, W1, W2)                \
  do {                                                                        \
    /* ph0 */                                                                 \
    RD_A(AOFF, 0);                                                            \
    RD_B(BOFF, 0);                                                            \
    if (STG) { STBE(SBOFF, 0, KTN); STBE(SBOFF, 1, KTN);                      \
               STA(SAOFF, 0, KTN); STA(SAOFF, 2, KTN); }                      \
    W0;                                                                       \
    LGKM8;                                                                    \
    BAR; LGKM0;                                                               \
    MFMA_Q(0, 0);                                                             \
    BAR;                                                                      \
    /* ph1 */                                                                 \
    RD_B(BOFF, 2);                                                            \
    if (STG) { STBO(SBOFF, 0, KTN); STBO(SBOFF, 1, KTN); }                    \
    W1;                                                                       \
    BAR; LGKM0;                                                               \
    MFMA_Q(0, 2);                                                             \
    BAR;                                                                      \
    /* ph2 */                                                                 \
    RD_A(AOFF, 1);                                                            \
    if (STG) { STA(SAOFF, 1, KTN); STA(SAOFF, 3, KTN); }                      \
    BAR; LGKM0;                                                               \
    MFMA_Q(4, 0);                                                             \
    BAR;                                                                      \
    /* ph3 */                                                                 \
    W2;                                                                       \
    BAR; LGKM0;                                                               \
    MFMA_Q(4, 2);                                                             \
    BAR;                                                                      \
  } while (0)

  f32x4 acc[8][4];
#pragma unroll
  for (int m = 0; m < 8; ++m)
#pragma unroll
    for (int n = 0; n < 4; ++n) acc[m][n] = (f32x4)(0.f);

  short8 ar[4][2], br[4][2];

  // ---- prologue: stage tile 0 into buf 0 in need-order; wait ev-four only ----
  STBE(16384, 0, 0); STBE(16384, 1, 0); STA(0, 0, 0); STA(0, 2, 0);
  STBO(16384, 0, 0); STBO(16384, 1, 0);
  STA(0, 1, 0); STA(0, 3, 0);
  VMC4;   // {Bev0,Bev1,A0,A2} landed; 4 in flight (loop invariant)
  BAR;    // publication

  for (int i = 0; i < 31; ++i) {
    K_TILE(0, 16384, 32768, 49152, (2 * i + 1) * 64, 1, VMC6, VMC6, VMC4);
    K_TILE(32768, 49152, 0, 16384, (2 * i + 2) * 64, 1, VMC6, VMC6, VMC4);
  }
  // tile 62 (buf0), stage tile 63 -> buf1
  K_TILE(0, 16384, 32768, 49152, 63 * 64, 1, VMC6, VMC6, VMC4);
  // tile 63 (buf1), no staging: drain waits
  K_TILE(32768, 49152, 0, 16384, 0, 0, VMC2, VMC0, WNONE);

  // ---- epilogue: out = acc*scale[col] + bias[col] ----
  const int r4 = q4 * 4;
#pragma unroll
  for (int n = 0; n < 4; ++n) {
    const int col = bn0 + wc * 64 + n * 16 + l15;
    const float sc = scale[col];
    const float bs = bias[col];
#pragma unroll
    for (int mi = 0; mi < 8; ++mi) {
      const int row = bm0 + wr * 128 + mi * 16 + r4;
#pragma unroll
      for (int j = 0; j < 4; ++j)
        C[(int64_t)(row + j) * KD + col] = acc[mi][n][j] * sc + bs;
    }
  }
}

extern "C" void kernel_launch(void* const* d_in, const int* in_sizes, int n_in,
                              void* d_out, int out_size, void* d_ws, size_t ws_size,
                              hipStream_t stream) {
  const float* x = (const float*)d_in[0];
  const int* q = (const int*)d_in[1];
  const float* scale = (const float*)d_in[2];
  const int* zp = (const int*)d_in[3];
  const float* bias = (const float*)d_in[4];
  float* out = (float*)d_out;

  u16* Xb = (u16*)d_ws;                    // 32 MiB
  u16* Qt = Xb + (size_t)4096 * 4096;      // 32 MiB

  cvt_fused<<<20480, 256, 0, stream>>>((const float4*)x, q, zp,
                                       (uint2*)Xb, Qt);

  gemm8<<<256, 512, 0, stream>>>(Xb, Qt, scale, bias, out);
}